// Round 9
// baseline (553.702 us; speedup 1.0000x reference)
//
#include <hip/hip_runtime.h>
#include <hip/hip_bf16.h>

// GATv2 x2 on MI355X. N=100000, E=3200000, D=128, H=1, C1=16, C2=32.
// Inputs f32; d_out f32, 3E floats = [edges(2E) | alpha2(E)].
// Round-15: edge2bin identified as pinned at the HBM random-64B transaction
// wall: 6.4M gathers / 137us = 3.0 TB/s (streaming=6.3, random-64B=~half).
// R8's occupancy fix moved it 141->137 only; FETCH 325MB is near-intrinsic
// (dst/src-ordered alternatives trade gathers for a ~205MB scattered write).
// This round consolidates everything else:
//  (a) bucket1f = bucket1 + fused lin2 epilogue (h staged in dead srt LDS,
//      W2 in 4KB LDS; kills out1 roundtrip + launch; LDS ~45KB, 3 blk/CU)
//  (b) final3 = final2 + edges passthrough (den2 moved to ws; one kernel
//      writes all 3E outputs; kills edges_kernel + 25.6MB re-read)
//
// d_out layout:
//  A [0,E):    e      score1 -> score2; final3 reads e[i] then writes out[i]
//  R [E,2E):   xl2/xr2 (N*64 bf16) -> overwritten by final3 dst passthrough
//  C [2E,3E):  den1(N) xl1(8N) xr1(8N); dead before final3 writes alpha2
// d_ws (~32.4MB; proven >=160MB): tmp uint2[782*5120] | gcur[782] | den2[N]

#define NN 100000
#define EE 3200000
#define DD 128
#define CC1 16
#define CC2 32
#define NEG_SLOPE 0.2f

#define NPB  128                        // nodes per bucket
#define NBK  782                        // ceil(NN/NPB); 782*128 = 100096
#define BCAP 5120                       // records/bucket (mean 4092, +16 sigma)
#define ACH  4096                       // edges per edge*bin block (8/thread @512)
#define ABLK 782                        // ceil(EE/ACH)

typedef __hip_bfloat16 bf16;

__device__ __forceinline__ float b2f(bf16 v) { return __bfloat162float(v); }

// load 8 consecutive bf16 -> 8 floats (one 16B load); bases verified 16B-aligned
__device__ __forceinline__ void ld8bf(const bf16* p, float* f) {
    uint4 u = *(const uint4*)p;
    const unsigned w[4] = {u.x, u.y, u.z, u.w};
#pragma unroll
    for (int i = 0; i < 4; i++) {
        f[2 * i]     = __uint_as_float(w[i] << 16);
        f[2 * i + 1] = __uint_as_float(w[i] & 0xffff0000u);
    }
}

// Order-preserving float<->uint encode for atomicMax (fallback path only).
__device__ __forceinline__ unsigned enc_f(float x) {
    unsigned b = __float_as_uint(x);
    return (b & 0x80000000u) ? ~b : (b | 0x80000000u);
}
__device__ __forceinline__ float dec_f(unsigned u) {
    unsigned b = (u & 0x80000000u) ? (u & 0x7fffffffu) : ~u;
    return __uint_as_float(b);
}

// ---------- Layer-1 node transform: xl1/xr1 = x@W + b (bf16 out) ----------
__global__ void lin1_kernel(const float* __restrict__ x,
                            const float* __restrict__ Wl, const float* __restrict__ bl,
                            const float* __restrict__ Wr, const float* __restrict__ br,
                            bf16* __restrict__ xl1, bf16* __restrict__ xr1) {
    __shared__ float Ws[DD][32];   // col<16: Wl, col>=16: Wr
    __shared__ float xs[8][DD];
    const int t = threadIdx.x;
    for (int i = t; i < DD * CC1; i += 256) {
        int k = i >> 4, c = i & 15;
        Ws[k][c]      = Wl[i];
        Ws[k][c + 16] = Wr[i];
    }
    const int node0 = blockIdx.x * 8;
    for (int i = t; i < 8 * DD; i += 256) {
        int n = i >> 7, k = i & 127;
        xs[n][k] = x[(node0 + n) * DD + k];
    }
    __syncthreads();
    const int n = t >> 5, c = t & 31;
    const int node = node0 + n;
    float acc = 0.f;
#pragma unroll 16
    for (int k = 0; k < DD; k++) acc += xs[n][k] * Ws[k][c];
    if (c < 16) xl1[node * CC1 + c]        = __float2bfloat16(acc + bl[c]);
    else        xr1[node * CC1 + (c - 16)] = __float2bfloat16(acc + br[c - 16]);
}

// ---------- FAST: Layer-1 edge scores fused with bucket binning ----------
// 512 threads x 8 edges; record = ( d&127 | src<<7 , e1 ); no global atomics.
__global__ void edge1bin_kernel(const int* __restrict__ edges,
                                const float* __restrict__ ew,
                                const bf16* __restrict__ xl1, const bf16* __restrict__ xr1,
                                const float* __restrict__ We1, const float* __restrict__ att1,
                                float* __restrict__ e1,
                                uint2* __restrict__ tmp, int* __restrict__ gcur) {
    __shared__ float Wes[CC1], atts[CC1];
    __shared__ int cnts[NBK], gbase[NBK], lfill[NBK];
    const int t = threadIdx.x;    // 512
    if (t < CC1) { Wes[t] = We1[t]; atts[t] = att1[t]; }
    for (int b = t; b < NBK; b += 512) { cnts[b] = 0; lfill[b] = 0; }
    __syncthreads();
    const int base = blockIdx.x * ACH;
    unsigned pk[8]; float ev[8]; int bk[8];
#pragma unroll
    for (int k = 0; k < 8; k++) {
        const int i = base + k * 512 + t;
        bk[k] = -1;
        if (i < EE) {
            const int s = edges[i], d = edges[EE + i];
            const float w = ew[i];
            float a[CC1], b[CC1];
            ld8bf(xl1 + s * CC1, a); ld8bf(xl1 + s * CC1 + 8, a + 8);
            ld8bf(xr1 + d * CC1, b); ld8bf(xr1 + d * CC1 + 8, b + 8);
            float acc = 0.f;
#pragma unroll
            for (int c = 0; c < CC1; c++) {
                float v = a[c] + b[c] + w * Wes[c];
                v = v > 0.f ? v : NEG_SLOPE * v;
                acc += v * atts[c];
            }
            e1[i] = acc;
            bk[k] = d >> 7;
            pk[k] = (unsigned)(d & 127) | ((unsigned)s << 7);
            ev[k] = acc;
            atomicAdd(&cnts[bk[k]], 1);
        }
    }
    __syncthreads();
    for (int b = t; b < NBK; b += 512)
        if (cnts[b] > 0) gbase[b] = atomicAdd(&gcur[b], cnts[b]);
    __syncthreads();
#pragma unroll
    for (int k = 0; k < 8; k++) {
        if (bk[k] >= 0) {
            const int slot = gbase[bk[k]] + atomicAdd(&lfill[bk[k]], 1);
            tmp[(size_t)bk[k] * BCAP + slot] = make_uint2(pk[k], __float_as_uint(ev[k]));
        }
    }
}

// ---------- FAST: fused bucket sort + per-node register agg + lin2 ----------
// Sort into 40KB LDS (2 LDS atomics/rec) -> per-node 16-lane register FMA ->
// h=relu(agg+b1) staged into dead srt LDS -> in-block 16x64 GEMM -> xl2/xr2.
__global__ void bucket1f_kernel(const uint2* __restrict__ tmp, const int* __restrict__ gcur,
                                const bf16* __restrict__ xl1,
                                const float* __restrict__ b1,
                                const float* __restrict__ Wl2, const float* __restrict__ bl2,
                                const float* __restrict__ Wr2, const float* __restrict__ br2,
                                float* __restrict__ den1,
                                bf16* __restrict__ xl2, bf16* __restrict__ xr2) {
    __shared__ int cnt[NPB];          // hist, then countdown cursor
    __shared__ int loff[NPB + 1];     // local exclusive prefix
    __shared__ uint2 srt[BCAP];       // 40KB sorted (src, p); reused as hbuf
    __shared__ float Ws[CC1][64];     // col<32: Wl2, col>=32: Wr2
    const int t = threadIdx.x;        // 512
    const int b = blockIdx.x;
    const int count = gcur[b];
    const uint2* rec = tmp + (size_t)b * BCAP;
    for (int i = t; i < CC1 * CC2; i += 512) {   // 512 exactly
        int k = i >> 5, c = i & 31;
        Ws[k][c]      = Wl2[i];
        Ws[k][c + 32] = Wr2[i];
    }
    for (int i = t; i < NPB; i += 512) cnt[i] = 0;
    __syncthreads();
    for (int j = t; j < count; j += 512) atomicAdd(&cnt[rec[j].x & 127u], 1);
    __syncthreads();
    if (t == 0) {
        int run = 0;
#pragma unroll
        for (int i = 0; i < NPB; i++) { loff[i] = run; run += cnt[i]; }
        loff[NPB] = run;
    }
    __syncthreads();
    for (int j = t; j < count; j += 512) {
        const uint2 r = rec[j];       // second read: L2-hot (40KB window)
        const int d = (int)(r.x & 127u);
        const int rr = atomicSub(&cnt[d], 1);           // rr in [1..deg]
        srt[loff[d] + rr - 1] =
            make_uint2(r.x >> 7, __float_as_uint(__expf(__uint_as_float(r.y))));
    }
    __syncthreads();
    const int g = t >> 4, c = t & 15; // 32 groups x 16 channel-lanes
    const int n0 = b * NPB;
    float hreg[4];                    // h for nodes g, g+32, g+64, g+96
#pragma unroll
    for (int it = 0; it < 4; it++) {
        const int dn = g + it * 32;
        const int beg = loff[dn], end = loff[dn + 1];
        float l = 0.f, acc = 0.f;
        for (int j = beg; j < end; j++) {
            const uint2 r = srt[j];               // broadcast across 16 lanes
            const float p = __uint_as_float(r.y);
            acc += p * b2f(xl1[r.x * CC1 + c]);   // 3.2MB table: L2-resident
            l += p;
        }
        const float h = (l > 0.f ? acc / l : 0.f) + b1[c];
        hreg[it] = h > 0.f ? h : 0.f;             // relu(out1 + b1)
        if (c == 0) {
            const int node = n0 + dn;
            if (node < NN) den1[node] = l;
        }
    }
    __syncthreads();                  // all srt reads done -> reuse as hbuf
    float* hbuf = (float*)srt;        // [NPB][17] (+1 pad)
#pragma unroll
    for (int it = 0; it < 4; it++) hbuf[(g + it * 32) * 17 + c] = hreg[it];
    __syncthreads();
    for (int i = t; i < NPB * 64; i += 512) {     // 16 iters: 128 nodes x 64 cols
        const int dn = i >> 6, cc = i & 63;       // dn uniform per wave
        const int node = n0 + dn;
        if (node >= NN) continue;
        float a2 = 0.f;
#pragma unroll
        for (int k = 0; k < CC1; k++) a2 += hbuf[dn * 17 + k] * Ws[k][cc];
        if (cc < 32) xl2[node * CC2 + cc]        = __float2bfloat16(a2 + bl2[cc]);
        else         xr2[node * CC2 + (cc - 32)] = __float2bfloat16(a2 + br2[cc - 32]);
    }
}

// ---------- FAST: Layer-2 edge scores fused with bucket binning ----------
// 512 threads x 8 edges; alpha1 = exp(e1)/den1 inline; record = ( d&127 , e2 ).
__global__ void edge2bin_kernel(const int* __restrict__ edges,
                                float* __restrict__ e,     // in: score1, out: score2
                                const float* __restrict__ den1,
                                const bf16* __restrict__ xl2, const bf16* __restrict__ xr2,
                                const float* __restrict__ We2, const float* __restrict__ att2,
                                uint2* __restrict__ tmp, int* __restrict__ gcur) {
    __shared__ float Wes[CC2], atts[CC2];
    __shared__ int cnts[NBK], gbase[NBK], lfill[NBK];
    const int t = threadIdx.x;    // 512
    if (t < CC2) { Wes[t] = We2[t]; atts[t] = att2[t]; }
    for (int b = t; b < NBK; b += 512) { cnts[b] = 0; lfill[b] = 0; }
    __syncthreads();
    const int base = blockIdx.x * ACH;
    unsigned pk[8]; float ev[8]; int bk[8];
#pragma unroll
    for (int k = 0; k < 8; k++) {
        const int i = base + k * 512 + t;
        bk[k] = -1;
        if (i < EE) {
            const int s = edges[i], d = edges[EE + i];
            const float w = __expf(e[i]) / (den1[d] + 1e-16f);  // alpha1, no shift
            float a[CC2], b[CC2];
#pragma unroll
            for (int q = 0; q < 4; q++) {
                ld8bf(xl2 + s * CC2 + 8 * q, a + 8 * q);
                ld8bf(xr2 + d * CC2 + 8 * q, b + 8 * q);
            }
            float acc = 0.f;
#pragma unroll
            for (int c = 0; c < CC2; c++) {
                float v = a[c] + b[c] + w * Wes[c];
                v = v > 0.f ? v : NEG_SLOPE * v;
                acc += v * atts[c];
            }
            e[i] = acc;
            bk[k] = d >> 7;
            pk[k] = (unsigned)(d & 127);
            ev[k] = acc;
            atomicAdd(&cnts[bk[k]], 1);
        }
    }
    __syncthreads();
    for (int b = t; b < NBK; b += 512)
        if (cnts[b] > 0) gbase[b] = atomicAdd(&gcur[b], cnts[b]);
    __syncthreads();
#pragma unroll
    for (int k = 0; k < 8; k++) {
        if (bk[k] >= 0) {
            const int slot = gbase[bk[k]] + atomicAdd(&lfill[bk[k]], 1);
            tmp[(size_t)bk[k] * BCAP + slot] = make_uint2(pk[k], __float_as_uint(ev[k]));
        }
    }
}

// ---------- FAST: per-bucket layer-2 denominator (1 LDS atomic/rec) ----------
__global__ void nodeB2_kernel(const uint2* __restrict__ tmp, const int* __restrict__ gcur,
                              float* __restrict__ den2) {
    __shared__ float den[NPB];
    const int t = threadIdx.x;            // 512
    const int b = blockIdx.x;
    const int count = gcur[b];
    const uint2* rec = tmp + (size_t)b * BCAP;
    for (int i = t; i < NPB; i += 512) den[i] = 0.f;
    __syncthreads();
    for (int j = t; j < count; j += 512) {
        const uint2 r = rec[j];
        atomicAdd(&den[r.x & 127u], __expf(__uint_as_float(r.y)));
    }
    __syncthreads();
    const int n0 = b * NPB;
    for (int i = t; i < NPB; i += 512) {
        const int node = n0 + i;
        if (node < NN) den2[node] = den[i];
    }
}

// ---------- FAST: all 3E outputs in one pass ----------
// out[i]=src, out[E+i]=dst (xl2/xr2 dead), out[2E+i]=alpha2. Thread i reads
// e[i] before overwriting out[i] (same thread, program order). den2 is in ws.
__global__ void final3_kernel(const int* __restrict__ edges,
                              const float* __restrict__ e,
                              const float* __restrict__ den2,
                              float* __restrict__ out) {
    const int i = blockIdx.x * 256 + threadIdx.x;
    const int s = edges[i], d = edges[EE + i];
    const float a2 = __expf(e[i]) / (den2[d] + 1e-16f);
    out[i]          = (float)s;
    out[EE + i]     = (float)d;
    out[2 * EE + i] = a2;
}

// ================= FALLBACK PATH (round-5/6, known-good) =================
__global__ void edge1f_kernel(const int* __restrict__ edges,
                              const float* __restrict__ ew,
                              const bf16* __restrict__ xl1, const bf16* __restrict__ xr1,
                              const float* __restrict__ We1, const float* __restrict__ att1,
                              float* __restrict__ e1, int* __restrict__ cnt,
                              unsigned* __restrict__ m1enc) {
    __shared__ float Wes[CC1], atts[CC1];
    if (threadIdx.x < CC1) {
        Wes[threadIdx.x]  = We1[threadIdx.x];
        atts[threadIdx.x] = att1[threadIdx.x];
    }
    __syncthreads();
    const int e = blockIdx.x * 256 + threadIdx.x;
    const int s = edges[e], d = edges[EE + e];
    const float w = ew[e];
    float a[CC1], b[CC1];
    ld8bf(xl1 + s * CC1, a); ld8bf(xl1 + s * CC1 + 8, a + 8);
    ld8bf(xr1 + d * CC1, b); ld8bf(xr1 + d * CC1 + 8, b + 8);
    float acc = 0.f;
#pragma unroll
    for (int c = 0; c < CC1; c++) {
        float v = a[c] + b[c] + w * Wes[c];
        v = v > 0.f ? v : NEG_SLOPE * v;
        acc += v * atts[c];
    }
    e1[e] = acc;
    atomicAdd(&cnt[d], 1);
    atomicMax(&m1enc[d], enc_f(acc));
}

__global__ void scan_kernel(const int* __restrict__ cnt, int* __restrict__ off) {
    __shared__ int part[1024];
    const int t = threadIdx.x;
    const int chunk = (NN + 1023) / 1024;
    const int beg = t * chunk;
    const int end = min(beg + chunk, NN);
    int s = 0;
    for (int i = beg; i < end; i++) s += cnt[i];
    part[t] = s;
    __syncthreads();
    for (int o = 1; o < 1024; o <<= 1) {
        int v = (t >= o) ? part[t - o] : 0;
        __syncthreads();
        part[t] += v;
        __syncthreads();
    }
    int run = (t > 0) ? part[t - 1] : 0;
    for (int i = beg; i < end; i++) { off[i] = run; run += cnt[i]; }
    if (t == 1023) off[NN] = part[1023];
}

__global__ void scatter_kernel(const int* __restrict__ edges,
                               const int* __restrict__ off, int* __restrict__ cnt,
                               int* __restrict__ csr) {
    const int i = blockIdx.x * 256 + threadIdx.x;
    const int d = edges[EE + i];
    const int r = atomicSub(&cnt[d], 1);
    csr[off[d] + r - 1] = i;
}

__global__ void node1s_kernel(const int* __restrict__ off, const int* __restrict__ csr,
                              const int* __restrict__ edges,
                              const float* __restrict__ e1, const bf16* __restrict__ xl1,
                              float* __restrict__ den1, bf16* __restrict__ out1) {
    const int t = blockIdx.x * 256 + threadIdx.x;
    const int n = t >> 4, c = t & 15;
    const int beg = off[n], end = off[n + 1];
    float m = -3.0e38f, l = 0.f, acc = 0.f;
    for (int j = beg; j < end; j++) {
        const int eid = csr[j];
        const float s = e1[eid];
        const int src = edges[eid];
        const float xv = b2f(xl1[src * CC1 + c]);
        if (s > m) { const float r = __expf(m - s); l *= r; acc *= r; m = s; }
        const float p = __expf(s - m);
        l += p; acc += p * xv;
    }
    out1[n * CC1 + c] = __float2bfloat16(l > 0.f ? acc / l : 0.f);
    if (c == 0) den1[n] = l;
}

__global__ void lin2_kernel(const bf16* __restrict__ out1, const float* __restrict__ b1,
                            const float* __restrict__ Wl2, const float* __restrict__ bl2,
                            const float* __restrict__ Wr2, const float* __restrict__ br2,
                            bf16* __restrict__ xl2, bf16* __restrict__ xr2) {
    __shared__ float Ws[CC1][64];
    __shared__ float hs[4][CC1];
    const int t = threadIdx.x;
    for (int i = t; i < CC1 * CC2; i += 256) {
        int k = i >> 5, c = i & 31;
        Ws[k][c]      = Wl2[i];
        Ws[k][c + 32] = Wr2[i];
    }
    const int node0 = blockIdx.x * 4;
    if (t < 64) {
        int n = t >> 4, k = t & 15;
        float v = b2f(out1[(node0 + n) * CC1 + k]) + b1[k];
        hs[n][k] = v > 0.f ? v : 0.f;
    }
    __syncthreads();
    const int n = t >> 6, c = t & 63;
    const int node = node0 + n;
    float acc = 0.f;
#pragma unroll
    for (int k = 0; k < CC1; k++) acc += hs[n][k] * Ws[k][c];
    if (c < 32) xl2[node * CC2 + c]        = __float2bfloat16(acc + bl2[c]);
    else        xr2[node * CC2 + (c - 32)] = __float2bfloat16(acc + br2[c - 32]);
}

__global__ void edge2enc_kernel(const int* __restrict__ edges,
                                float* __restrict__ e,
                                const unsigned* __restrict__ m1enc,
                                const float* __restrict__ den1,
                                const bf16* __restrict__ xl2, const bf16* __restrict__ xr2,
                                const float* __restrict__ We2, const float* __restrict__ att2) {
    __shared__ float Wes[CC2], atts[CC2];
    if (threadIdx.x < CC2) {
        Wes[threadIdx.x]  = We2[threadIdx.x];
        atts[threadIdx.x] = att2[threadIdx.x];
    }
    __syncthreads();
    const int i = blockIdx.x * 256 + threadIdx.x;
    const int s = edges[i], d = edges[EE + i];
    const float w = __expf(e[i] - dec_f(m1enc[d])) / (den1[d] + 1e-16f);
    float a[CC2], b[CC2];
#pragma unroll
    for (int q = 0; q < 4; q++) {
        ld8bf(xl2 + s * CC2 + 8 * q, a + 8 * q);
        ld8bf(xr2 + d * CC2 + 8 * q, b + 8 * q);
    }
    float acc = 0.f;
#pragma unroll
    for (int c = 0; c < CC2; c++) {
        float v = a[c] + b[c] + w * Wes[c];
        v = v > 0.f ? v : NEG_SLOPE * v;
        acc += v * atts[c];
    }
    e[i] = acc;
}

__global__ void max2_kernel(const int* __restrict__ dst, const float* __restrict__ e2,
                            unsigned* __restrict__ m2) {
    const int i = blockIdx.x * 256 + threadIdx.x;
    atomicMax(&m2[dst[i]], enc_f(e2[i]));
}

__global__ void num2_kernel(const int* __restrict__ dst,
                            const unsigned* __restrict__ m2,
                            float* __restrict__ e, float* __restrict__ den2) {
    const int i = blockIdx.x * 256 + threadIdx.x;
    const int d = dst[i];
    const float v = __expf(e[i] - dec_f(m2[d]));
    e[i] = v;
    atomicAdd(&den2[d], v);
}

__global__ void finalold_kernel(const int* __restrict__ dst,
                                const float* __restrict__ e,
                                const float* __restrict__ den2,
                                float* __restrict__ out) {
    const int i = blockIdx.x * 256 + threadIdx.x;
    const int d = dst[i];
    out[2 * EE + i] = e[i] / (den2[d] + 1e-16f);
}

__global__ void edges_kernel(const int* __restrict__ edges, float* __restrict__ out) {
    const int i = blockIdx.x * 256 + threadIdx.x;
    out[i] = (float)edges[i];
}

extern "C" void kernel_launch(void* const* d_in, const int* in_sizes, int n_in,
                              void* d_out, int out_size, void* d_ws, size_t ws_size,
                              hipStream_t stream) {
    const float* x    = (const float*)d_in[0];
    const int*  edges = (const int*)d_in[1];
    const float* ew   = (const float*)d_in[2];
    const float* Wl1  = (const float*)d_in[3];
    const float* bl1  = (const float*)d_in[4];
    const float* Wr1  = (const float*)d_in[5];
    const float* br1  = (const float*)d_in[6];
    const float* We1  = (const float*)d_in[7];
    const float* att1 = (const float*)d_in[8];
    const float* b1   = (const float*)d_in[9];
    const float* Wl2  = (const float*)d_in[10];
    const float* bl2  = (const float*)d_in[11];
    const float* Wr2  = (const float*)d_in[12];
    const float* br2  = (const float*)d_in[13];
    const float* We2  = (const float*)d_in[14];
    const float* att2 = (const float*)d_in[15];
    float* out = (float*)d_out;

    const int* dst = edges + EE;
    const int EG = EE / 256;                          // 12500

    // ---- Workspace: tmp(32MB) | gcur | den2(400KB) ----
    const size_t dpBytes = (size_t)NBK * BCAP * 8;
    uint2* tmp    = (uint2*)d_ws;
    int*   gcur   = (int*)((char*)d_ws + dpBytes);
    float* den2ws = (float*)((char*)d_ws + dpBytes + 8192);
    const size_t ws_need = dpBytes + 8192 + (size_t)NN * sizeof(float);
    const bool fast = (d_ws != nullptr) && (ws_size >= ws_need);

    if (fast) {
        // ---- fast layout ----
        float* e = out;                               // [0,E)
        bf16*  xl2  = (bf16*)(out + EE);              // R: N*32 bf16
        bf16*  xr2  = xl2 + NN * CC2;                 // R: N*32 bf16
        float* den1 = out + 2 * EE;                   // C region
        bf16*  xl1  = (bf16*)(den1 + NN);             // 16B-aligned
        bf16*  xr1  = xl1 + NN * CC1;

        hipMemsetAsync(gcur, 0, (size_t)NBK * sizeof(int), stream);
        lin1_kernel    <<<NN / 8, 256, 0, stream>>>(x, Wl1, bl1, Wr1, br1, xl1, xr1);
        edge1bin_kernel<<<ABLK, 512, 0, stream>>>(edges, ew, xl1, xr1, We1, att1,
                                                  e, tmp, gcur);
        bucket1f_kernel<<<NBK, 512, 0, stream>>>(tmp, gcur, xl1, b1,
                                                 Wl2, bl2, Wr2, br2,
                                                 den1, xl2, xr2);
        hipMemsetAsync(gcur, 0, (size_t)NBK * sizeof(int), stream);
        edge2bin_kernel<<<ABLK, 512, 0, stream>>>(edges, e, den1, xl2, xr2,
                                                  We2, att2, tmp, gcur);
        nodeB2_kernel  <<<NBK, 512, 0, stream>>>(tmp, gcur, den2ws);
        final3_kernel  <<<EG, 256, 0, stream>>>(edges, e, den2ws, out);
    } else {
        // ---- fallback layout (round-6) ----
        float*    e    = out;
        int*      csr  = (int*)(out + EE);
        bf16*     xl2  = (bf16*)(out + EE);
        bf16*     xr2  = xl2 + NN * CC2;
        unsigned* m2   = (unsigned*)(out + EE);
        float*    den2 = (float*)(out + EE) + NN;
        int*      offF  = (int*)(out + 2 * EE);
        unsigned* m1enc = (unsigned*)(offF + NN + 4);
        int*      cnt   = (int*)(m1enc + NN);
        float*    den1  = (float*)(cnt + NN);
        bf16*     xl1   = (bf16*)(den1 + NN);
        bf16*     xr1   = xl1 + NN * CC1;
        bf16*     out1  = xr1 + NN * CC1;

        hipMemsetAsync(m1enc, 0, (size_t)2 * NN * sizeof(int), stream);  // m1enc+cnt
        lin1_kernel   <<<NN / 8, 256, 0, stream>>>(x, Wl1, bl1, Wr1, br1, xl1, xr1);
        edge1f_kernel <<<EG, 256, 0, stream>>>(edges, ew, xl1, xr1, We1, att1,
                                               e, cnt, m1enc);
        scan_kernel   <<<1, 1024, 0, stream>>>(cnt, offF);
        scatter_kernel<<<EG, 256, 0, stream>>>(edges, offF, cnt, csr);
        node1s_kernel <<<NN * 16 / 256, 256, 0, stream>>>(offF, csr, edges, e, xl1,
                                                          den1, out1);
        lin2_kernel   <<<NN / 4, 256, 0, stream>>>(out1, b1, Wl2, bl2, Wr2, br2, xl2, xr2);
        edge2enc_kernel<<<EG, 256, 0, stream>>>(edges, e, m1enc, den1, xl2, xr2,
                                                We2, att2);
        hipMemsetAsync(m2, 0, (size_t)2 * NN * sizeof(float), stream);
        max2_kernel   <<<EG, 256, 0, stream>>>(dst, e, m2);
        num2_kernel   <<<EG, 256, 0, stream>>>(dst, m2, e, den2);
        finalold_kernel<<<EG, 256, 0, stream>>>(dst, e, den2, out);
        edges_kernel  <<<2 * EG, 256, 0, stream>>>(edges, out);
    }
}